// Round 1
// baseline (238.788 us; speedup 1.0000x reference)
//
#include <hip/hip_runtime.h>

typedef unsigned short u16;
typedef unsigned int u32;
typedef __bf16 bf16x8 __attribute__((ext_vector_type(8)));
typedef float f32x4 __attribute__((ext_vector_type(4)));

#define L2E 1.44269504088896340736f

__device__ __forceinline__ u16 f2bf(float f) {
  u32 u = __float_as_uint(f);
  u32 r = (u + 0x7fffu + ((u >> 16) & 1u)) >> 16;
  return (u16)r;
}
__device__ __forceinline__ float bf2f(u32 bits) {
  return __uint_as_float(bits << 16);
}

// ---------------- f32 -> bf16 conversion ----------------
__global__ __launch_bounds__(256) void cvt_f32_bf16(const float* __restrict__ src,
                                                    u16* __restrict__ dst, int n) {
  int i = (blockIdx.x * 256 + threadIdx.x) * 8;
  if (i + 8 > n) return;
  float4 a = *(const float4*)(src + i);
  float4 b = *(const float4*)(src + i + 4);
  union { u16 h[8]; uint4 v; } o;
  o.h[0] = f2bf(a.x); o.h[1] = f2bf(a.y); o.h[2] = f2bf(a.z); o.h[3] = f2bf(a.w);
  o.h[4] = f2bf(b.x); o.h[5] = f2bf(b.y); o.h[6] = f2bf(b.z); o.h[7] = f2bf(b.w);
  *(uint4*)(dst + i) = o.v;
}

// ---------------- shared GEMM helpers (128x128 tile, BK=64, 4 waves) ----------------
__device__ __forceinline__ void stage128x64(const u16* __restrict__ src, int ld,
                                            short* lds, int t) {
  int w = t >> 6;
#pragma unroll
  for (int i = 0; i < 4; ++i) {
    int c = i * 256 + t;             // 16B chunk id, 1024 chunks = 16KB
    int row = c >> 3, col = (c & 7) * 8;
    int cbase = i * 256 + w * 64;    // wave-uniform chunk base
    __builtin_amdgcn_global_load_lds(
        (const __attribute__((address_space(1))) void*)(src + (size_t)row * ld + col),
        (__attribute__((address_space(3))) void*)(lds + (size_t)cbase * 8),
        16, 0, 0);
  }
}

__device__ __forceinline__ void mfma_step(const short* sA, const short* sB,
                                          int lane, int wr, int wc, f32x4 acc[4][4]) {
  int lm = lane & 15, lk = (lane >> 4) * 8;
#pragma unroll
  for (int kk = 0; kk < 2; ++kk) {
    bf16x8 af[4], bfr[4];
#pragma unroll
    for (int i = 0; i < 4; ++i)
      af[i] = *(const bf16x8*)(sA + (wr + i * 16 + lm) * 64 + kk * 32 + lk);
#pragma unroll
    for (int i = 0; i < 4; ++i)
      bfr[i] = *(const bf16x8*)(sB + (wc + i * 16 + lm) * 64 + kk * 32 + lk);
#pragma unroll
    for (int mi = 0; mi < 4; ++mi)
#pragma unroll
      for (int ni = 0; ni < 4; ++ni)
        acc[mi][ni] = __builtin_amdgcn_mfma_f32_16x16x32_bf16(af[mi], bfr[ni], acc[mi][ni], 0, 0, 0);
  }
}

// ---------------- Kernel A: QKV GEMM + mask epilogue ----------------
// qkv[r, e] = sum_d xb[r,d] * wqkv[e,d];  r = b*4096+n
__global__ __launch_bounds__(256) void qkv_gemm(const u16* __restrict__ xb,
                                                const u16* __restrict__ wb,
                                                u16* __restrict__ qkv,
                                                const int* __restrict__ lengths) {
  __shared__ short sA[128 * 64];
  __shared__ short sB[128 * 64];
  int t = threadIdx.x;
  int row0 = blockIdx.x * 128;
  int col0 = blockIdx.y * 128;
  f32x4 acc[4][4] = {};
  const u16* pa = xb + (size_t)row0 * 512;
  const u16* pb = wb + (size_t)col0 * 512;
  int lane = t & 63, w = t >> 6;
  int wr = (w >> 1) * 64, wc = (w & 1) * 64;
  for (int kt = 0; kt < 8; ++kt) {
    stage128x64(pa + kt * 64, 512, sA, t);
    stage128x64(pb + kt * 64, 512, sB, t);
    __syncthreads();
    mfma_step(sA, sB, lane, wr, wc, acc);
    __syncthreads();
  }
  int L = lengths[row0 >> 12];
  int lm = lane & 15;
#pragma unroll
  for (int mi = 0; mi < 4; ++mi) {
#pragma unroll
    for (int r = 0; r < 4; ++r) {
      int grow = row0 + wr + mi * 16 + ((lane >> 4) * 4) + r;
      bool masked = (grow & 4095) >= L;
      size_t rb = (size_t)grow * 1536;
#pragma unroll
      for (int ni = 0; ni < 4; ++ni) {
        int gcol = col0 + wc + ni * 16 + lm;
        float v = acc[mi][ni][r];
        if (gcol < 512) v = masked ? 0.f : v * 0.125f;      // q: scale + mask
        else if (masked) v = (gcol < 1024) ? -1e15f : 0.f;  // k -> NEG, v -> 0
        qkv[rb + gcol] = f2bf(v);
      }
    }
  }
}

// ---------------- B1: per-(b,c) partial max / sumexp over 128-row chunks ----------------
__global__ __launch_bounds__(256) void rowstat(const u16* __restrict__ qkv,
                                               float* __restrict__ pmax,
                                               float* __restrict__ psum) {
  int chunk = blockIdx.x;  // 0..31
  int b = blockIdx.y;      // 0..7
  int t = threadIdx.x;
  const u16* base = qkv + (size_t)(b * 4096 + chunk * 128) * 1536 + 512 + 2 * t;
  float m0 = -3e38f, m1 = -3e38f;
  for (int r = 0; r < 128; ++r) {
    u32 u = *(const u32*)(base + (size_t)r * 1536);
    m0 = fmaxf(m0, bf2f(u & 0xffffu));
    m1 = fmaxf(m1, bf2f(u >> 16));
  }
  float s0 = 0.f, s1 = 0.f;
  for (int r = 0; r < 128; ++r) {
    u32 u = *(const u32*)(base + (size_t)r * 1536);
    s0 += exp2f((bf2f(u & 0xffffu) - m0) * L2E);
    s1 += exp2f((bf2f(u >> 16) - m1) * L2E);
  }
  int idx = (b * 32 + chunk) * 512 + 2 * t;
  pmax[idx] = m0; pmax[idx + 1] = m1;
  psum[idx] = s0; psum[idx + 1] = s1;
}

// ---------------- B1b: combine partials -> gmax, denom ----------------
__global__ __launch_bounds__(256) void combine(const float* __restrict__ pmax,
                                               const float* __restrict__ psum,
                                               float* __restrict__ gmax,
                                               float* __restrict__ denom) {
  int b = blockIdx.x;
  int t = threadIdx.x;
#pragma unroll
  for (int rep = 0; rep < 2; ++rep) {
    int c = t + rep * 256;
    float m = -3e38f;
    for (int i = 0; i < 32; ++i) m = fmaxf(m, pmax[(size_t)(b * 32 + i) * 512 + c]);
    float s = 0.f;
    for (int i = 0; i < 32; ++i) {
      float pm = pmax[(size_t)(b * 32 + i) * 512 + c];
      s += psum[(size_t)(b * 32 + i) * 512 + c] * exp2f((pm - m) * L2E);
    }
    gmax[b * 512 + c] = m;
    denom[b * 512 + c] = s;
  }
}

// ---------------- B2: ctx partials: ctx[d,e] += exp(k[n,d]-gmax[d]) * v[n,e] ----------------
__global__ __launch_bounds__(256) void ctx_gemm(const u16* __restrict__ qkv,
                                                const float* __restrict__ gmax,
                                                float* __restrict__ ctxp) {
  int chunk = blockIdx.x;  // 0..7 (512 rows each)
  int bh = blockIdx.y;     // 0..63
  int b = bh >> 3, h = bh & 7;
  int t = threadIdx.x;
  __shared__ float g2[64];
  __shared__ float kx[32][64];
  __shared__ float vx[32][64];
  if (t < 64) g2[t] = gmax[b * 512 + h * 64 + t] * L2E;
  float acc[4][4] = {};
  int d0 = (t & 15) * 4;
  int e0 = (t >> 4) * 4;
  int srow = t >> 3, scol = (t & 7) * 8;
  const u16* base = qkv + (size_t)(b * 4096 + chunk * 512) * 1536 + 512 + h * 64;
  for (int g = 0; g < 16; ++g) {
    __syncthreads();
    const u16* kp = base + (size_t)(g * 32 + srow) * 1536 + scol;
    uint4 kvr = *(const uint4*)kp;
    uint4 vvr = *(const uint4*)(kp + 512);
    u32 kw[4] = {kvr.x, kvr.y, kvr.z, kvr.w};
    u32 vw[4] = {vvr.x, vvr.y, vvr.z, vvr.w};
#pragma unroll
    for (int i = 0; i < 4; ++i) {
      float k0 = bf2f(kw[i] & 0xffffu), k1 = bf2f(kw[i] >> 16);
      kx[srow][scol + 2 * i] = exp2f(__fmaf_rn(k0, L2E, -g2[scol + 2 * i]));
      kx[srow][scol + 2 * i + 1] = exp2f(__fmaf_rn(k1, L2E, -g2[scol + 2 * i + 1]));
      vx[srow][scol + 2 * i] = bf2f(vw[i] & 0xffffu);
      vx[srow][scol + 2 * i + 1] = bf2f(vw[i] >> 16);
    }
    __syncthreads();
#pragma unroll 4
    for (int nn = 0; nn < 32; ++nn) {
      f32x4 p = *(const f32x4*)&kx[nn][d0];
      f32x4 vv = *(const f32x4*)&vx[nn][e0];
#pragma unroll
      for (int i = 0; i < 4; ++i)
#pragma unroll
        for (int j = 0; j < 4; ++j)
          acc[i][j] = __fmaf_rn(p[i], vv[j], acc[i][j]);
    }
  }
  float* outp = ctxp + ((size_t)bh * 8 + chunk) * 4096;
#pragma unroll
  for (int i = 0; i < 4; ++i)
#pragma unroll
    for (int j = 0; j < 4; ++j)
      outp[(d0 + i) * 64 + (e0 + j)] = acc[i][j];
}

// ---------------- B3: MT[b][dd][64h+d] = sum_e (ctx[d,e]/denom[d]) * w_out[dd][64h+e] ----------------
__global__ __launch_bounds__(256) void m_gemm(const float* __restrict__ ctxp,
                                              const float* __restrict__ denom,
                                              const float* __restrict__ w_out,
                                              u16* __restrict__ MT) {
  int bh = blockIdx.x;   // 0..63
  int grp = blockIdx.y;  // 0..3
  int b = bh >> 3, h = bh & 7;
  int dd0 = grp * 128;
  int t = threadIdx.x;
  __shared__ short sctx[64 * 64];   // [d][e] bf16, ctx/denom
  __shared__ short sw[128 * 64];    // [dd_local][e] bf16
  {
    const float* cp = ctxp + (size_t)bh * 8 * 4096;
    int i0 = t * 16;
    float vals[16] = {};
#pragma unroll
    for (int ch = 0; ch < 8; ++ch) {
      const float* p = cp + ch * 4096 + i0;
#pragma unroll
      for (int j = 0; j < 16; j += 4) {
        float4 v = *(const float4*)(p + j);
        vals[j] += v.x; vals[j + 1] += v.y; vals[j + 2] += v.z; vals[j + 3] += v.w;
      }
    }
    int d = i0 >> 6;
    float rin = 1.0f / denom[b * 512 + h * 64 + d];
#pragma unroll
    for (int j = 0; j < 16; ++j) sctx[i0 + j] = (short)f2bf(vals[j] * rin);
  }
  {
#pragma unroll
    for (int j = 0; j < 32; j += 4) {
      int idx = t * 32 + j;
      int row = idx >> 6, col = idx & 63;
      float4 v = *(const float4*)(w_out + (size_t)(dd0 + row) * 512 + h * 64 + col);
      sw[idx] = (short)f2bf(v.x); sw[idx + 1] = (short)f2bf(v.y);
      sw[idx + 2] = (short)f2bf(v.z); sw[idx + 3] = (short)f2bf(v.w);
    }
  }
  __syncthreads();
  int lane = t & 63, w = t >> 6;
  int lm = lane & 15, lk = (lane >> 4) * 8;
  f32x4 acc[2][4] = {};
#pragma unroll
  for (int kk = 0; kk < 2; ++kk) {
    bf16x8 af[2], bfr[4];
#pragma unroll
    for (int mb = 0; mb < 2; ++mb)
      af[mb] = *(const bf16x8*)(sw + (w * 32 + mb * 16 + lm) * 64 + kk * 32 + lk);
#pragma unroll
    for (int nb = 0; nb < 4; ++nb)
      bfr[nb] = *(const bf16x8*)(sctx + (nb * 16 + lm) * 64 + kk * 32 + lk);
#pragma unroll
    for (int mb = 0; mb < 2; ++mb)
#pragma unroll
      for (int nb = 0; nb < 4; ++nb)
        acc[mb][nb] = __builtin_amdgcn_mfma_f32_16x16x32_bf16(af[mb], bfr[nb], acc[mb][nb], 0, 0, 0);
  }
  u16* outp = MT + (size_t)b * 512 * 512;
#pragma unroll
  for (int mb = 0; mb < 2; ++mb)
#pragma unroll
    for (int r = 0; r < 4; ++r) {
      int dd = dd0 + w * 32 + mb * 16 + (lane >> 4) * 4 + r;
#pragma unroll
      for (int nb = 0; nb < 4; ++nb) {
        int c = h * 64 + nb * 16 + lm;
        outp[dd * 512 + c] = f2bf(acc[mb][nb][r]);
      }
    }
}

// ---------------- Kernel C: out[b,n,dd] = sum_c q[b,n,c]*MT[b,dd,c] + b_out[dd] ----------------
__global__ __launch_bounds__(256) void out_gemm(const u16* __restrict__ qkv,
                                                const u16* __restrict__ MT,
                                                const float* __restrict__ b_out,
                                                float* __restrict__ out) {
  __shared__ short sA[128 * 64];
  __shared__ short sB[128 * 64];
  int t = threadIdx.x;
  int row0 = blockIdx.x * 128;   // over 32768
  int col0 = blockIdx.y * 128;   // over 512
  int b = row0 >> 12;
  f32x4 acc[4][4] = {};
  const u16* pa = qkv + (size_t)row0 * 1536;  // q section cols [0,512)
  const u16* pb = MT + (size_t)b * 512 * 512 + (size_t)col0 * 512;
  int lane = t & 63, w = t >> 6;
  int wr = (w >> 1) * 64, wc = (w & 1) * 64;
  for (int kt = 0; kt < 8; ++kt) {
    stage128x64(pa + kt * 64, 1536, sA, t);
    stage128x64(pb + kt * 64, 512, sB, t);
    __syncthreads();
    mfma_step(sA, sB, lane, wr, wc, acc);
    __syncthreads();
  }
  int lm = lane & 15;
  float bo[4];
#pragma unroll
  for (int ni = 0; ni < 4; ++ni) bo[ni] = b_out[col0 + wc + ni * 16 + lm];
#pragma unroll
  for (int mi = 0; mi < 4; ++mi)
#pragma unroll
    for (int r = 0; r < 4; ++r) {
      int grow = row0 + wr + mi * 16 + (lane >> 4) * 4 + r;
      size_t ob = (size_t)grow * 512;
#pragma unroll
      for (int ni = 0; ni < 4; ++ni)
        out[ob + col0 + wc + ni * 16 + lm] = acc[mi][ni][r] + bo[ni];
    }
}

extern "C" void kernel_launch(void* const* d_in, const int* in_sizes, int n_in,
                              void* d_out, int out_size, void* d_ws, size_t ws_size,
                              hipStream_t stream) {
  const float* x = (const float*)d_in[0];
  const float* w_qkv = (const float*)d_in[1];
  const float* w_out = (const float*)d_in[2];
  const float* b_out = (const float*)d_in[3];
  const int* lengths = (const int*)d_in[4];
  float* out = (float*)d_out;
  char* ws = (char*)d_ws;

  u16* qkv    = (u16*)(ws);                     // 32768*1536 bf16 = 100,663,296 B
  u16* xb     = (u16*)(ws + 100663296);         // 16.8M bf16 = 33,554,432 B
  u16* wqkvb  = (u16*)(ws + 134217728);         // 1,572,864 B
  float* pmax = (float*)(ws + 135790592);       // 8*32*512 f32 = 524,288 B
  float* psum = (float*)(ws + 136314880);       // 524,288 B
  float* gmax = (float*)(ws + 136839168);       // 16,384 B
  float* denom= (float*)(ws + 136855552);       // 16,384 B
  float* ctxp = (float*)(ws + 136871936);       // 64*8*4096 f32 = 8,388,608 B
  u16* MT     = (u16*)(ws + 145260544);         // 8*512*512 bf16 = 4,194,304 B

  cvt_f32_bf16<<<8192, 256, 0, stream>>>(x, xb, 16777216);
  cvt_f32_bf16<<<384, 256, 0, stream>>>(w_qkv, wqkvb, 786432);
  qkv_gemm<<<dim3(256, 12), 256, 0, stream>>>(xb, wqkvb, qkv, lengths);
  rowstat<<<dim3(32, 8), 256, 0, stream>>>(qkv, pmax, psum);
  combine<<<8, 256, 0, stream>>>(pmax, psum, gmax, denom);
  ctx_gemm<<<dim3(8, 64), 256, 0, stream>>>(qkv, gmax, ctxp);
  m_gemm<<<dim3(64, 4), 256, 0, stream>>>(ctxp, denom, w_out, MT);
  out_gemm<<<dim3(256, 4), 256, 0, stream>>>(qkv, MT, b_out, out);
}

// Round 2
// 184.548 us; speedup vs baseline: 1.2939x; 1.2939x over previous
//
#include <hip/hip_runtime.h>

typedef unsigned short u16;
typedef unsigned int u32;
typedef __bf16 bf16x8 __attribute__((ext_vector_type(8)));
typedef float f32x4 __attribute__((ext_vector_type(4)));

#define L2E 1.44269504088896340736f

static __device__ __forceinline__ u16 f2bf(float f) {
  u32 u = __float_as_uint(f);
  u32 r = (u + 0x7fffu + ((u >> 16) & 1u)) >> 16;
  return (u16)r;
}
static __device__ __forceinline__ float bf2f(u32 bits) {
  return __uint_as_float(bits << 16);
}

// ---------------- f32 -> bf16 conversion ----------------
__global__ __launch_bounds__(256) void cvt_f32_bf16(const float* __restrict__ src,
                                                    u16* __restrict__ dst, int n) {
  int i = (blockIdx.x * 256 + threadIdx.x) * 8;
  if (i + 8 > n) return;
  float4 a = *(const float4*)(src + i);
  float4 b = *(const float4*)(src + i + 4);
  union { u16 h[8]; uint4 v; } o;
  o.h[0] = f2bf(a.x); o.h[1] = f2bf(a.y); o.h[2] = f2bf(a.z); o.h[3] = f2bf(a.w);
  o.h[4] = f2bf(b.x); o.h[5] = f2bf(b.y); o.h[6] = f2bf(b.z); o.h[7] = f2bf(b.w);
  *(uint4*)(dst + i) = o.v;
}

// ---------------- 256x256 tile GEMM, BK=64, 8 waves, dbuf LDS, T2 swizzle ----------------
// C[r, c] = sum_k A[r,k] * B[c,k]   (B given row-major as [c][k])
// EPI=0: qkv epilogue (mask + scale, bf16 store, ldc=1536)
// EPI=1: out epilogue (bias add, f32 store, ldc=512; B base offset by batch)
template <int EPI>
__global__ __launch_bounds__(512, 2) void gemm256(const u16* __restrict__ A,
                                                  const u16* __restrict__ Bm,
                                                  u16* __restrict__ outb,
                                                  float* __restrict__ outf,
                                                  const float* __restrict__ bias,
                                                  const int* __restrict__ lengths,
                                                  int lda, int ldb) {
  __shared__ u16 lA[2][2][8192];  // [dbuf][half(row 0-127 / 128-255)][128*64 swizzled]
  __shared__ u16 lB[2][2][8192];

  const int t = threadIdx.x;
  const int w = t >> 6, lane = t & 63, lm = lane & 15, lg = lane >> 4;
  const int wr = w >> 2, wc = w & 3;  // wave grid 2 (M) x 4 (N)
  const int row0 = blockIdx.x * 256, col0 = blockIdx.y * 256;

  const u16* Abase = A + (size_t)row0 * lda;
  const u16* Bbase;
  if constexpr (EPI == 0) Bbase = Bm + (size_t)col0 * ldb;
  else Bbase = Bm + (size_t)(row0 >> 12) * 262144 + (size_t)col0 * ldb;

  // staging geometry: half-tile = 128 rows x 64 cols bf16 = 1024 x 16B chunks
  // chunk j: row=j>>3, 16B-slot=(j&7)^((j>>3)&7)  (inverse of read-side swizzle)
  const int r0 = t >> 3;                       // 0..63
  const int slot = (t & 7) ^ (r0 & 7);
  const size_t aoff0 = (size_t)r0 * lda + slot * 8;
  const size_t aoff1 = (size_t)(r0 + 64) * lda + slot * 8;
  const size_t boff0 = (size_t)r0 * ldb + slot * 8;
  const size_t boff1 = (size_t)(r0 + 64) * ldb + slot * 8;
  const int ldst0 = (w * 64) * 8;              // wave-uniform LDS chunk base (u16 units)
  const int ldst1 = (512 + w * 64) * 8;

  auto stA = [&](int buf, int half, int kt) {
    const u16* s = Abase + (size_t)(half * 128) * lda + kt * 64;
    __builtin_amdgcn_global_load_lds(
        (const __attribute__((address_space(1))) void*)(s + aoff0),
        (__attribute__((address_space(3))) void*)(&lA[buf][half][ldst0]), 16, 0, 0);
    __builtin_amdgcn_global_load_lds(
        (const __attribute__((address_space(1))) void*)(s + aoff1),
        (__attribute__((address_space(3))) void*)(&lA[buf][half][ldst1]), 16, 0, 0);
  };
  auto stB = [&](int buf, int half, int kt) {
    const u16* s = Bbase + (size_t)(half * 128) * ldb + kt * 64;
    __builtin_amdgcn_global_load_lds(
        (const __attribute__((address_space(1))) void*)(s + boff0),
        (__attribute__((address_space(3))) void*)(&lB[buf][half][ldst0]), 16, 0, 0);
    __builtin_amdgcn_global_load_lds(
        (const __attribute__((address_space(1))) void*)(s + boff1),
        (__attribute__((address_space(3))) void*)(&lB[buf][half][ldst1]), 16, 0, 0);
  };

  // read-side swizzled 16B-slot offsets (u16 units): slot' = (kk*4+lg) ^ (lm&7)
  const int swz0 = ((lg) ^ (lm & 7)) * 8;
  const int swz1 = ((4 + lg) ^ (lm & 7)) * 8;

  f32x4 acc[8][4] = {};

  // prologue: stage K-tile 0 fully
  stA(0, 0, 0); stA(0, 1, 0); stB(0, 0, 0); stB(0, 1, 0);
  __syncthreads();

#pragma unroll 2
  for (int kt = 0; kt < 8; ++kt) {
    const int cur = kt & 1, nxt = cur ^ 1;
    const bool pf = (kt < 7);
    const u16* la = &lA[cur][wr][lm * 64];
    const u16* lb = &lB[cur][wc >> 1][(wc & 1) * 4096 + lm * 64];

    bf16x8 bfr[2][4];
#pragma unroll
    for (int nf = 0; nf < 4; ++nf) {
      bfr[0][nf] = *(const bf16x8*)(lb + nf * 1024 + swz0);
      bfr[1][nf] = *(const bf16x8*)(lb + nf * 1024 + swz1);
    }
#pragma unroll
    for (int ph = 0; ph < 4; ++ph) {
      if (pf) {  // spread next-tile staging across phases (issue-early)
        if (ph == 0) stA(nxt, 0, kt + 1);
        else if (ph == 1) stA(nxt, 1, kt + 1);
        else if (ph == 2) stB(nxt, 0, kt + 1);
        else stB(nxt, 1, kt + 1);
      }
      bf16x8 af[2][2];
#pragma unroll
      for (int m2 = 0; m2 < 2; ++m2) {
        af[m2][0] = *(const bf16x8*)(la + (ph * 2 + m2) * 1024 + swz0);
        af[m2][1] = *(const bf16x8*)(la + (ph * 2 + m2) * 1024 + swz1);
      }
      __builtin_amdgcn_s_setprio(1);
#pragma unroll
      for (int m2 = 0; m2 < 2; ++m2)
#pragma unroll
        for (int nf = 0; nf < 4; ++nf)
#pragma unroll
          for (int kk = 0; kk < 2; ++kk)
            // swapped operands: D row-index <- B rows (n), col-index <- A rows (m)
            acc[ph * 2 + m2][nf] = __builtin_amdgcn_mfma_f32_16x16x32_bf16(
                bfr[kk][nf], af[m2][kk], acc[ph * 2 + m2][nf], 0, 0, 0);
      __builtin_amdgcn_s_setprio(0);
    }
    __syncthreads();  // drains this wave's 8 prefetch loads (issued >=1 phase ago)
  }

  // lane holds C[row = base_m + lm][col = base_n + lg*4 + r]  (4 consecutive cols)
  if constexpr (EPI == 0) {
    const int L = lengths[row0 >> 12];
    const int cls = col0 >> 9;  // 0=q, 1=k, 2=v (uniform per block)
#pragma unroll
    for (int mf = 0; mf < 8; ++mf) {
      int grow = row0 + wr * 128 + mf * 16 + lm;
      bool msk = ((grow & 4095) >= L);
      u16* rp = outb + (size_t)grow * 1536 + col0 + wc * 64 + lg * 4;
#pragma unroll
      for (int nf = 0; nf < 4; ++nf) {
        f32x4 v = acc[mf][nf];
        if (cls == 0) {
#pragma unroll
          for (int r = 0; r < 4; ++r) v[r] = msk ? 0.f : v[r] * 0.125f;
        } else if (cls == 1) {
          if (msk) { v[0] = -1e15f; v[1] = -1e15f; v[2] = -1e15f; v[3] = -1e15f; }
        } else {
          if (msk) { v[0] = 0.f; v[1] = 0.f; v[2] = 0.f; v[3] = 0.f; }
        }
        union { u16 h[4]; uint2 u; } pk;
        pk.h[0] = f2bf(v[0]); pk.h[1] = f2bf(v[1]);
        pk.h[2] = f2bf(v[2]); pk.h[3] = f2bf(v[3]);
        *(uint2*)(rp + nf * 16) = pk.u;
      }
    }
  } else {
    f32x4 b4[4];
#pragma unroll
    for (int nf = 0; nf < 4; ++nf)
      b4[nf] = *(const f32x4*)(bias + col0 + wc * 64 + nf * 16 + lg * 4);
#pragma unroll
    for (int mf = 0; mf < 8; ++mf) {
      int grow = row0 + wr * 128 + mf * 16 + lm;
      float* rp = outf + (size_t)grow * 512 + col0 + wc * 64 + lg * 4;
#pragma unroll
      for (int nf = 0; nf < 4; ++nf) {
        f32x4 v = acc[mf][nf] + b4[nf];
        *(f32x4*)(rp + nf * 16) = v;
      }
    }
  }
}

// ---------------- B2: ctx partials + per-chunk denominator partial sums ----------------
// ctx[d,e] += exp(k[n,d]) * v[n,e];  csum[d] += exp(k[n,d])   (no max: k is O(1), masked = -1e15 -> 0)
__global__ __launch_bounds__(256) void ctx_gemm(const u16* __restrict__ qkv,
                                                float* __restrict__ ctxp,
                                                float* __restrict__ csum) {
  int chunk = blockIdx.x;  // 0..7 (512 rows each)
  int bh = blockIdx.y;     // 0..63
  int b = bh >> 3, h = bh & 7;
  int t = threadIdx.x;
  __shared__ float kx[32][64];
  __shared__ float vx[32][64];
  float acc[4][4] = {};
  float sacc[4] = {};
  int d0 = (t & 15) * 4;
  int e0 = (t >> 4) * 4;
  bool do_sum = ((t >> 4) == 0);
  int srow = t >> 3, scol = (t & 7) * 8;
  const u16* base = qkv + (size_t)(b * 4096 + chunk * 512) * 1536 + 512 + h * 64;
  for (int g = 0; g < 16; ++g) {
    __syncthreads();
    const u16* kp = base + (size_t)(g * 32 + srow) * 1536 + scol;
    uint4 kvr = *(const uint4*)kp;
    uint4 vvr = *(const uint4*)(kp + 512);
    u32 kw[4] = {kvr.x, kvr.y, kvr.z, kvr.w};
    u32 vw[4] = {vvr.x, vvr.y, vvr.z, vvr.w};
#pragma unroll
    for (int i = 0; i < 4; ++i) {
      float k0 = bf2f(kw[i] & 0xffffu), k1 = bf2f(kw[i] >> 16);
      kx[srow][scol + 2 * i] = exp2f(k0 * L2E);
      kx[srow][scol + 2 * i + 1] = exp2f(k1 * L2E);
      vx[srow][scol + 2 * i] = bf2f(vw[i] & 0xffffu);
      vx[srow][scol + 2 * i + 1] = bf2f(vw[i] >> 16);
    }
    __syncthreads();
#pragma unroll 4
    for (int nn = 0; nn < 32; ++nn) {
      f32x4 p = *(const f32x4*)&kx[nn][d0];
      f32x4 vv = *(const f32x4*)&vx[nn][e0];
      if (do_sum) {
#pragma unroll
        for (int i = 0; i < 4; ++i) sacc[i] += p[i];
      }
#pragma unroll
      for (int i = 0; i < 4; ++i)
#pragma unroll
        for (int j = 0; j < 4; ++j)
          acc[i][j] = __fmaf_rn(p[i], vv[j], acc[i][j]);
    }
  }
  float* outp = ctxp + ((size_t)bh * 8 + chunk) * 4096;
#pragma unroll
  for (int i = 0; i < 4; ++i)
#pragma unroll
    for (int j = 0; j < 4; ++j)
      outp[(d0 + i) * 64 + (e0 + j)] = acc[i][j];
  if (t < 16) {
#pragma unroll
    for (int i = 0; i < 4; ++i)
      csum[((size_t)bh * 8 + chunk) * 64 + d0 + i] = sacc[i];
  }
}

// ---------------- B3: MT[b][dd][64h+d] = sum_e (ctx[d,e]/denom[d]) * w_out[dd][64h+e] ----------------
__global__ __launch_bounds__(256) void m_gemm(const float* __restrict__ ctxp,
                                              const float* __restrict__ csum,
                                              const float* __restrict__ w_out,
                                              u16* __restrict__ MT) {
  int bh = blockIdx.x;   // 0..63
  int grp = blockIdx.y;  // 0..3
  int b = bh >> 3, h = bh & 7;
  int dd0 = grp * 128;
  int t = threadIdx.x;
  __shared__ short sctx[64 * 64];   // [d][e] bf16, ctx/denom
  __shared__ short sw[128 * 64];    // [dd_local][e] bf16
  {
    const float* cp = ctxp + (size_t)bh * 8 * 4096;
    int i0 = t * 16;
    float vals[16] = {};
#pragma unroll
    for (int ch = 0; ch < 8; ++ch) {
      const float* p = cp + ch * 4096 + i0;
#pragma unroll
      for (int j = 0; j < 16; j += 4) {
        float4 v = *(const float4*)(p + j);
        vals[j] += v.x; vals[j + 1] += v.y; vals[j + 2] += v.z; vals[j + 3] += v.w;
      }
    }
    int d = t >> 2;
    float den = 0.f;
#pragma unroll
    for (int ch = 0; ch < 8; ++ch) den += csum[((size_t)bh * 8 + ch) * 64 + d];
    float rin = 1.0f / den;
#pragma unroll
    for (int j = 0; j < 16; ++j) sctx[i0 + j] = (short)f2bf(vals[j] * rin);
  }
  {
#pragma unroll
    for (int j = 0; j < 32; j += 4) {
      int idx = t * 32 + j;
      int row = idx >> 6, col = idx & 63;
      float4 v = *(const float4*)(w_out + (size_t)(dd0 + row) * 512 + h * 64 + col);
      sw[idx] = (short)f2bf(v.x); sw[idx + 1] = (short)f2bf(v.y);
      sw[idx + 2] = (short)f2bf(v.z); sw[idx + 3] = (short)f2bf(v.w);
    }
  }
  __syncthreads();
  int lane = t & 63, w = t >> 6;
  int lm = lane & 15, lk = (lane >> 4) * 8;
  f32x4 acc[2][4] = {};
#pragma unroll
  for (int kk = 0; kk < 2; ++kk) {
    bf16x8 af[2], bfr[4];
#pragma unroll
    for (int mb = 0; mb < 2; ++mb)
      af[mb] = *(const bf16x8*)(sw + (w * 32 + mb * 16 + lm) * 64 + kk * 32 + lk);
#pragma unroll
    for (int nb = 0; nb < 4; ++nb)
      bfr[nb] = *(const bf16x8*)(sctx + (nb * 16 + lm) * 64 + kk * 32 + lk);
#pragma unroll
    for (int mb = 0; mb < 2; ++mb)
#pragma unroll
      for (int nb = 0; nb < 4; ++nb)
        acc[mb][nb] = __builtin_amdgcn_mfma_f32_16x16x32_bf16(af[mb], bfr[nb], acc[mb][nb], 0, 0, 0);
  }
  u16* outp = MT + (size_t)b * 512 * 512;
#pragma unroll
  for (int mb = 0; mb < 2; ++mb)
#pragma unroll
    for (int r = 0; r < 4; ++r) {
      int dd = dd0 + w * 32 + mb * 16 + (lane >> 4) * 4 + r;
#pragma unroll
      for (int nb = 0; nb < 4; ++nb) {
        int c = h * 64 + nb * 16 + lm;
        outp[dd * 512 + c] = f2bf(acc[mb][nb][r]);
      }
    }
}

extern "C" void kernel_launch(void* const* d_in, const int* in_sizes, int n_in,
                              void* d_out, int out_size, void* d_ws, size_t ws_size,
                              hipStream_t stream) {
  const float* x = (const float*)d_in[0];
  const float* w_qkv = (const float*)d_in[1];
  const float* w_out = (const float*)d_in[2];
  const float* b_out = (const float*)d_in[3];
  const int* lengths = (const int*)d_in[4];
  float* out = (float*)d_out;
  char* ws = (char*)d_ws;

  u16* qkv    = (u16*)(ws);                     // 32768*1536 bf16 = 100,663,296 B
  u16* xb     = (u16*)(ws + 100663296);         // 33,554,432 B
  u16* wqkvb  = (u16*)(ws + 134217728);         // 1,572,864 B
  float* ctxp = (float*)(ws + 135790592);       // 64*8*4096 f32 = 8,388,608 B
  float* csum = (float*)(ws + 144179200);       // 64*8*64 f32 = 131,072 B
  u16* MT     = (u16*)(ws + 144310272);         // 8*512*512 bf16 = 4,194,304 B

  cvt_f32_bf16<<<8192, 256, 0, stream>>>(x, xb, 16777216);
  cvt_f32_bf16<<<384, 256, 0, stream>>>(w_qkv, wqkvb, 786432);
  gemm256<0><<<dim3(128, 6), 512, 0, stream>>>(xb, wqkvb, qkv, nullptr, nullptr,
                                               lengths, 512, 512);
  ctx_gemm<<<dim3(8, 64), 256, 0, stream>>>(qkv, ctxp, csum);
  m_gemm<<<dim3(64, 4), 256, 0, stream>>>(ctxp, csum, w_out, MT);
  gemm256<1><<<dim3(128, 2), 512, 0, stream>>>(qkv, MT, nullptr, out, b_out,
                                               nullptr, 1536, 512);
}

// Round 3
// 182.774 us; speedup vs baseline: 1.3065x; 1.0097x over previous
//
#include <hip/hip_runtime.h>

typedef unsigned short u16;
typedef unsigned int u32;
typedef __bf16 bf16x8 __attribute__((ext_vector_type(8)));
typedef float f32x4 __attribute__((ext_vector_type(4)));

#define L2E 1.44269504088896340736f

static __device__ __forceinline__ u16 f2bf(float f) {
  u32 u = __float_as_uint(f);
  u32 r = (u + 0x7fffu + ((u >> 16) & 1u)) >> 16;
  return (u16)r;
}
static __device__ __forceinline__ float bf2f(u32 bits) {
  return __uint_as_float(bits << 16);
}

// ---------------- f32 -> bf16 conversion (generic, for w_qkv) ----------------
__global__ __launch_bounds__(256) void cvt_f32_bf16(const float* __restrict__ src,
                                                    u16* __restrict__ dst, int n) {
  int i = (blockIdx.x * 256 + threadIdx.x) * 8;
  if (i + 8 > n) return;
  float4 a = *(const float4*)(src + i);
  float4 b = *(const float4*)(src + i + 4);
  union { u16 h[8]; uint4 v; } o;
  o.h[0] = f2bf(a.x); o.h[1] = f2bf(a.y); o.h[2] = f2bf(a.z); o.h[3] = f2bf(a.w);
  o.h[4] = f2bf(b.x); o.h[5] = f2bf(b.y); o.h[6] = f2bf(b.z); o.h[7] = f2bf(b.w);
  *(uint4*)(dst + i) = o.v;
}

// ---------------- x -> bf16 with row skip (rows >= length never used) ----------------
__global__ __launch_bounds__(256) void cvt_x(const float* __restrict__ src,
                                             u16* __restrict__ dst,
                                             const int* __restrict__ lengths) {
  int i = (blockIdx.x * 256 + threadIdx.x) * 8;  // n = 16777216
  int row = i >> 9;                              // 512 f32 per row
  if ((row & 4095) >= lengths[row >> 12]) return;
  float4 a = *(const float4*)(src + i);
  float4 b = *(const float4*)(src + i + 4);
  union { u16 h[8]; uint4 v; } o;
  o.h[0] = f2bf(a.x); o.h[1] = f2bf(a.y); o.h[2] = f2bf(a.z); o.h[3] = f2bf(a.w);
  o.h[4] = f2bf(b.x); o.h[5] = f2bf(b.y); o.h[6] = f2bf(b.z); o.h[7] = f2bf(b.w);
  *(uint4*)(dst + i) = o.v;
}

// ---------------- pipelined GEMM: BM=128, BN=256, BK=64, 3-stage, depth-2 vmcnt ----------------
// C[r,c] = sum_k A[r,k]*B[c,k].  EPI=0: qkv epilogue; EPI=1: out epilogue (+bias, f32)
template <int EPI>
__global__ __launch_bounds__(512, 1) void gemm_pipe(const u16* __restrict__ A,
                                                    const u16* __restrict__ Bm,
                                                    u16* __restrict__ outb,
                                                    float* __restrict__ outf,
                                                    const float* __restrict__ bias,
                                                    const int* __restrict__ lengths,
                                                    int lda, int ldb) {
  __shared__ u16 lA[3][8192];   // 3 x 16KB  (128x64 tile, 16B-granule swizzled)
  __shared__ u16 lB[3][16384];  // 3 x 32KB  (256x64 tile)

  const int t = threadIdx.x;
  const int w = t >> 6, lane = t & 63, lm = lane & 15, lg = lane >> 4;
  const int wr = w >> 2, wc = w & 3;  // 2 (M) x 4 (N) wave grid
  const int row0 = blockIdx.x * 128, col0 = blockIdx.y * 256;
  const int L = lengths[row0 >> 12];
  const int n0 = row0 & 4095;

  if (n0 >= L) {
    if constexpr (EPI == 1) {
      // masked rows: out = bias exactly
      for (int i = t; i < 8192; i += 512) {
        int r = i >> 6, c = (i & 63) * 4;
        f32x4 bv = *(const f32x4*)(bias + col0 + c);
        *(f32x4*)(outf + (size_t)(row0 + r) * 512 + col0 + c) = bv;
      }
    }
    return;
  }

  const u16* Abase = A + (size_t)row0 * lda;
  const u16* Bbase;
  if constexpr (EPI == 0) Bbase = Bm + (size_t)col0 * ldb;
  else Bbase = Bm + (size_t)(row0 >> 12) * 262144 + (size_t)col0 * ldb;

  // staging: granule c (16B) holds source (row=c>>3, slot=(c&7)^(row&7)); dest linear
  size_t aoff[2], boff[4];
#pragma unroll
  for (int i = 0; i < 2; ++i) {
    int c = i * 512 + t, r = c >> 3, s = (c & 7) ^ (r & 7);
    aoff[i] = (size_t)r * lda + s * 8;
  }
#pragma unroll
  for (int i = 0; i < 4; ++i) {
    int c = i * 512 + t, r = c >> 3, s = (c & 7) ^ (r & 7);
    boff[i] = (size_t)r * ldb + s * 8;
  }

  auto stage = [&](int st, int kt) {  // 6 global_load_lds per thread
    const u16* sa = Abase + kt * 64;
#pragma unroll
    for (int i = 0; i < 2; ++i)
      __builtin_amdgcn_global_load_lds(
          (const __attribute__((address_space(1))) void*)(sa + aoff[i]),
          (__attribute__((address_space(3))) void*)(&lA[st][(i * 512 + w * 64) * 8]),
          16, 0, 0);
    const u16* sb = Bbase + kt * 64;
#pragma unroll
    for (int i = 0; i < 4; ++i)
      __builtin_amdgcn_global_load_lds(
          (const __attribute__((address_space(1))) void*)(sb + boff[i]),
          (__attribute__((address_space(3))) void*)(&lB[st][(i * 512 + w * 64) * 8]),
          16, 0, 0);
  };

  const int swz0 = (lg ^ (lm & 7)) * 8;        // u16 offsets of 16B slots
  const int swz1 = ((4 + lg) ^ (lm & 7)) * 8;

  f32x4 acc[4][4] = {};

  auto compute = [&](int st) {
    const u16* la = &lA[st][(wr * 64 + lm) * 64];
    const u16* lb = &lB[st][(wc * 64 + lm) * 64];
    bf16x8 bfr[2][4], af[4][2];
#pragma unroll
    for (int nf = 0; nf < 4; ++nf) {
      bfr[0][nf] = *(const bf16x8*)(lb + nf * 1024 + swz0);
      bfr[1][nf] = *(const bf16x8*)(lb + nf * 1024 + swz1);
    }
#pragma unroll
    for (int mf = 0; mf < 4; ++mf) {
      af[mf][0] = *(const bf16x8*)(la + mf * 1024 + swz0);
      af[mf][1] = *(const bf16x8*)(la + mf * 1024 + swz1);
    }
    __builtin_amdgcn_s_setprio(1);
#pragma unroll
    for (int mf = 0; mf < 4; ++mf)
#pragma unroll
      for (int nf = 0; nf < 4; ++nf)
#pragma unroll
        for (int kk = 0; kk < 2; ++kk)
          acc[mf][nf] = __builtin_amdgcn_mfma_f32_16x16x32_bf16(
              bfr[kk][nf], af[mf][kk], acc[mf][nf], 0, 0, 0);
    __builtin_amdgcn_s_setprio(0);
  };

  // prologue: 2 tiles in flight
  stage(0, 0);
  stage(1, 1);

#define GTILE(KT, VMS)                                       \
  {                                                          \
    if ((KT) + 2 < 8) stage(((KT) + 2) % 3, (KT) + 2);       \
    asm volatile("s_waitcnt vmcnt(" VMS ")" ::: "memory");   \
    __builtin_amdgcn_s_barrier();                            \
    compute((KT) % 3);                                       \
    asm volatile("s_waitcnt lgkmcnt(0)" ::: "memory");       \
    __builtin_amdgcn_s_barrier();                            \
  }
  GTILE(0, "12") GTILE(1, "12") GTILE(2, "12") GTILE(3, "12")
  GTILE(4, "12") GTILE(5, "12") GTILE(6, "6") GTILE(7, "0")
#undef GTILE

  // lane holds C[row = rowbase + lm][col = colbase + lg*4 + r]
  if constexpr (EPI == 0) {
    const int cls = col0 >> 9;  // 0=q, 1=k, 2=v (uniform per block)
#pragma unroll
    for (int mf = 0; mf < 4; ++mf) {
      int grow = row0 + wr * 64 + mf * 16 + lm;
      bool msk = ((grow & 4095) >= L);
      u16* rp = outb + (size_t)grow * 1536 + col0 + wc * 64 + lg * 4;
#pragma unroll
      for (int nf = 0; nf < 4; ++nf) {
        f32x4 v = acc[mf][nf];
        if (cls == 0) {
#pragma unroll
          for (int r = 0; r < 4; ++r) v[r] = msk ? 0.f : v[r] * 0.125f;
        } else if (cls == 1) {
          if (msk) { v[0] = -1e15f; v[1] = -1e15f; v[2] = -1e15f; v[3] = -1e15f; }
        } else {
          if (msk) { v[0] = 0.f; v[1] = 0.f; v[2] = 0.f; v[3] = 0.f; }
        }
        union { u16 h[4]; uint2 u; } pk;
        pk.h[0] = f2bf(v[0]); pk.h[1] = f2bf(v[1]);
        pk.h[2] = f2bf(v[2]); pk.h[3] = f2bf(v[3]);
        *(uint2*)(rp + nf * 16) = pk.u;
      }
    }
  } else {
    f32x4 b4[4];
#pragma unroll
    for (int nf = 0; nf < 4; ++nf)
      b4[nf] = *(const f32x4*)(bias + col0 + wc * 64 + nf * 16 + lg * 4);
#pragma unroll
    for (int mf = 0; mf < 4; ++mf) {
      int grow = row0 + wr * 64 + mf * 16 + lm;
      float* rp = outf + (size_t)grow * 512 + col0 + wc * 64 + lg * 4;
#pragma unroll
      for (int nf = 0; nf < 4; ++nf) {
        f32x4 v = acc[mf][nf] + b4[nf];
        *(f32x4*)(rp + nf * 16) = v;
      }
    }
  }
}

// ---------------- B2: ctx partials + denominator partials (length-aware) ----------------
__global__ __launch_bounds__(256) void ctx_gemm(const u16* __restrict__ qkv,
                                                float* __restrict__ ctxp,
                                                float* __restrict__ csum,
                                                const int* __restrict__ lengths) {
  int chunk = blockIdx.x;  // 0..7 (512 rows each)
  int bh = blockIdx.y;     // 0..63
  int b = bh >> 3, h = bh & 7;
  int L = lengths[b];
  int rows = L - chunk * 512;
  if (rows <= 0) return;
  int ng = rows >= 512 ? 16 : ((rows + 31) >> 5);
  int t = threadIdx.x;
  __shared__ float kx[32][64];
  __shared__ float vx[32][64];
  float acc[4][4] = {};
  float sacc[4] = {};
  int d0 = (t & 15) * 4;
  int e0 = (t >> 4) * 4;
  bool do_sum = ((t >> 4) == 0);
  int srow = t >> 3, scol = (t & 7) * 8;
  const u16* base = qkv + (size_t)(b * 4096 + chunk * 512) * 1536 + 512 + h * 64;
  for (int g = 0; g < ng; ++g) {
    __syncthreads();
    const u16* kp = base + (size_t)(g * 32 + srow) * 1536 + scol;
    uint4 kvr = *(const uint4*)kp;
    uint4 vvr = *(const uint4*)(kp + 512);
    u32 kw[4] = {kvr.x, kvr.y, kvr.z, kvr.w};
    u32 vw[4] = {vvr.x, vvr.y, vvr.z, vvr.w};
#pragma unroll
    for (int i = 0; i < 4; ++i) {
      float k0 = bf2f(kw[i] & 0xffffu), k1 = bf2f(kw[i] >> 16);
      kx[srow][scol + 2 * i] = exp2f(k0 * L2E);
      kx[srow][scol + 2 * i + 1] = exp2f(k1 * L2E);
      vx[srow][scol + 2 * i] = bf2f(vw[i] & 0xffffu);
      vx[srow][scol + 2 * i + 1] = bf2f(vw[i] >> 16);
    }
    __syncthreads();
#pragma unroll 4
    for (int nn = 0; nn < 32; ++nn) {
      f32x4 p = *(const f32x4*)&kx[nn][d0];
      f32x4 vv = *(const f32x4*)&vx[nn][e0];
      if (do_sum) {
#pragma unroll
        for (int i = 0; i < 4; ++i) sacc[i] += p[i];
      }
#pragma unroll
      for (int i = 0; i < 4; ++i)
#pragma unroll
        for (int j = 0; j < 4; ++j)
          acc[i][j] = __fmaf_rn(p[i], vv[j], acc[i][j]);
    }
  }
  float* outp = ctxp + ((size_t)bh * 8 + chunk) * 4096;
#pragma unroll
  for (int i = 0; i < 4; ++i)
#pragma unroll
    for (int j = 0; j < 4; ++j)
      outp[(d0 + i) * 64 + (e0 + j)] = acc[i][j];
  if (t < 16) {
#pragma unroll
    for (int i = 0; i < 4; ++i)
      csum[((size_t)bh * 8 + chunk) * 64 + d0 + i] = sacc[i];
  }
}

// ---------------- B3: MT[b][dd][64h+d] = sum_e (ctx[d,e]/denom[d]) * w_out[dd][64h+e] ----------------
__global__ __launch_bounds__(256) void m_gemm(const float* __restrict__ ctxp,
                                              const float* __restrict__ csum,
                                              const float* __restrict__ w_out,
                                              u16* __restrict__ MT,
                                              const int* __restrict__ lengths) {
  int bh = blockIdx.x;   // 0..63
  int grp = blockIdx.y;  // 0..3
  int b = bh >> 3, h = bh & 7;
  int nch = (lengths[b] + 511) >> 9;  // 1..8 active chunks
  int dd0 = grp * 128;
  int t = threadIdx.x;
  __shared__ short sctx[64 * 64];
  __shared__ short sw[128 * 64];
  {
    const float* cp = ctxp + (size_t)bh * 8 * 4096;
    int i0 = t * 16;
    float vals[16] = {};
    for (int ch = 0; ch < nch; ++ch) {
      const float* p = cp + ch * 4096 + i0;
#pragma unroll
      for (int j = 0; j < 16; j += 4) {
        float4 v = *(const float4*)(p + j);
        vals[j] += v.x; vals[j + 1] += v.y; vals[j + 2] += v.z; vals[j + 3] += v.w;
      }
    }
    int d = t >> 2;
    float den = 0.f;
    for (int ch = 0; ch < nch; ++ch) den += csum[((size_t)bh * 8 + ch) * 64 + d];
    float rin = 1.0f / den;
#pragma unroll
    for (int j = 0; j < 16; ++j) sctx[i0 + j] = (short)f2bf(vals[j] * rin);
  }
  {
#pragma unroll
    for (int j = 0; j < 32; j += 4) {
      int idx = t * 32 + j;
      int row = idx >> 6, col = idx & 63;
      float4 v = *(const float4*)(w_out + (size_t)(dd0 + row) * 512 + h * 64 + col);
      sw[idx] = (short)f2bf(v.x); sw[idx + 1] = (short)f2bf(v.y);
      sw[idx + 2] = (short)f2bf(v.z); sw[idx + 3] = (short)f2bf(v.w);
    }
  }
  __syncthreads();
  int lane = t & 63, w = t >> 6;
  int lm = lane & 15, lk = (lane >> 4) * 8;
  f32x4 acc[2][4] = {};
#pragma unroll
  for (int kk = 0; kk < 2; ++kk) {
    bf16x8 af[2], bfr[4];
#pragma unroll
    for (int mb = 0; mb < 2; ++mb)
      af[mb] = *(const bf16x8*)(sw + (w * 32 + mb * 16 + lm) * 64 + kk * 32 + lk);
#pragma unroll
    for (int nb = 0; nb < 4; ++nb)
      bfr[nb] = *(const bf16x8*)(sctx + (nb * 16 + lm) * 64 + kk * 32 + lk);
#pragma unroll
    for (int mb = 0; mb < 2; ++mb)
#pragma unroll
      for (int nb = 0; nb < 4; ++nb)
        acc[mb][nb] = __builtin_amdgcn_mfma_f32_16x16x32_bf16(af[mb], bfr[nb], acc[mb][nb], 0, 0, 0);
  }
  u16* outp = MT + (size_t)b * 512 * 512;
#pragma unroll
  for (int mb = 0; mb < 2; ++mb)
#pragma unroll
    for (int r = 0; r < 4; ++r) {
      int dd = dd0 + w * 32 + mb * 16 + (lane >> 4) * 4 + r;
#pragma unroll
      for (int nb = 0; nb < 4; ++nb) {
        int c = h * 64 + nb * 16 + lm;
        outp[dd * 512 + c] = f2bf(acc[mb][nb][r]);
      }
    }
}

extern "C" void kernel_launch(void* const* d_in, const int* in_sizes, int n_in,
                              void* d_out, int out_size, void* d_ws, size_t ws_size,
                              hipStream_t stream) {
  const float* x = (const float*)d_in[0];
  const float* w_qkv = (const float*)d_in[1];
  const float* w_out = (const float*)d_in[2];
  const float* b_out = (const float*)d_in[3];
  const int* lengths = (const int*)d_in[4];
  float* out = (float*)d_out;
  char* ws = (char*)d_ws;

  u16* qkv    = (u16*)(ws);                     // 100,663,296 B
  u16* xb     = (u16*)(ws + 100663296);         // 33,554,432 B
  u16* wqkvb  = (u16*)(ws + 134217728);         // 1,572,864 B
  float* ctxp = (float*)(ws + 135790592);       // 8,388,608 B
  float* csum = (float*)(ws + 144179200);       // 131,072 B
  u16* MT     = (u16*)(ws + 144310272);         // 4,194,304 B

  cvt_x<<<8192, 256, 0, stream>>>(x, xb, lengths);
  cvt_f32_bf16<<<384, 256, 0, stream>>>(w_qkv, wqkvb, 786432);
  gemm_pipe<0><<<dim3(256, 6), 512, 0, stream>>>(xb, wqkvb, qkv, nullptr, nullptr,
                                                 lengths, 512, 512);
  ctx_gemm<<<dim3(8, 64), 256, 0, stream>>>(qkv, ctxp, csum, lengths);
  m_gemm<<<dim3(64, 4), 256, 0, stream>>>(ctxp, csum, w_out, MT, lengths);
  gemm_pipe<1><<<dim3(256, 2), 512, 0, stream>>>(qkv, MT, nullptr, out, b_out,
                                                 lengths, 1536, 512);
}

// Round 4
// 163.713 us; speedup vs baseline: 1.4586x; 1.1164x over previous
//
#include <hip/hip_runtime.h>

typedef unsigned short u16;
typedef unsigned int u32;
typedef __bf16 bf16x8 __attribute__((ext_vector_type(8)));
typedef float f32x4 __attribute__((ext_vector_type(4)));

#define L2E 1.44269504088896340736f

static __device__ __forceinline__ u16 f2bf(float f) {
  u32 u = __float_as_uint(f);
  u32 r = (u + 0x7fffu + ((u >> 16) & 1u)) >> 16;
  return (u16)r;
}
static __device__ __forceinline__ float bf2f(u32 bits) {
  return __uint_as_float(bits << 16);
}

// ---------------- f32 -> bf16 (for w_qkv k,v rows) ----------------
__global__ __launch_bounds__(256) void cvt_f32_bf16(const float* __restrict__ src,
                                                    u16* __restrict__ dst, int n) {
  int i = (blockIdx.x * 256 + threadIdx.x) * 8;
  if (i + 8 > n) return;
  float4 a = *(const float4*)(src + i);
  float4 b = *(const float4*)(src + i + 4);
  union { u16 h[8]; uint4 v; } o;
  o.h[0] = f2bf(a.x); o.h[1] = f2bf(a.y); o.h[2] = f2bf(a.z); o.h[3] = f2bf(a.w);
  o.h[4] = f2bf(b.x); o.h[5] = f2bf(b.y); o.h[6] = f2bf(b.z); o.h[7] = f2bf(b.w);
  *(uint4*)(dst + i) = o.v;
}

// ---------------- x -> bf16 with row skip ----------------
__global__ __launch_bounds__(256) void cvt_x(const float* __restrict__ src,
                                             u16* __restrict__ dst,
                                             const int* __restrict__ lengths) {
  int i = (blockIdx.x * 256 + threadIdx.x) * 8;  // n = 16777216
  int row = i >> 9;
  if ((row & 4095) >= lengths[row >> 12]) return;
  float4 a = *(const float4*)(src + i);
  float4 b = *(const float4*)(src + i + 4);
  union { u16 h[8]; uint4 v; } o;
  o.h[0] = f2bf(a.x); o.h[1] = f2bf(a.y); o.h[2] = f2bf(a.z); o.h[3] = f2bf(a.w);
  o.h[4] = f2bf(b.x); o.h[5] = f2bf(b.y); o.h[6] = f2bf(b.z); o.h[7] = f2bf(b.w);
  *(uint4*)(dst + i) = o.v;
}

// ---------------- wqT[s][c] = bf16(w_qkv[c][s]), 512x512 ----------------
__global__ __launch_bounds__(256) void transpose_wq(const float* __restrict__ wq,
                                                    u16* __restrict__ wqT) {
  __shared__ u16 tile[64][65];
  int c0 = blockIdx.x * 64, s0 = blockIdx.y * 64;
  int t = threadIdx.x;
  int r = t >> 4, cc = (t & 15) * 4;
#pragma unroll
  for (int i = 0; i < 4; ++i) {
    int row = r + i * 16;
    float4 v = *(const float4*)(wq + (size_t)(c0 + row) * 512 + s0 + cc);
    tile[row][cc] = f2bf(v.x); tile[row][cc + 1] = f2bf(v.y);
    tile[row][cc + 2] = f2bf(v.z); tile[row][cc + 3] = f2bf(v.w);
  }
  __syncthreads();
#pragma unroll
  for (int i = 0; i < 4; ++i) {
    int srow = r + i * 16;
    union { u16 h[4]; uint2 u; } pk;
#pragma unroll
    for (int j = 0; j < 4; ++j) pk.h[j] = tile[cc + j][srow];
    *(uint2*)(wqT + (size_t)(s0 + srow) * 512 + c0 + cc) = pk.u;
  }
}

// ---------------- GEMM: BM=128, BN=256, BK=64, single-buf 48KiB, 2 blocks/CU ----------------
// C[r,c] = sum_k A[r,k]*B[c,k], lda=ldb=512, K=512.
// MODE 0: kv epilogue (k->-1e15 / v->0 for masked rows, bf16, ldc=1024)
// MODE 1: plain bf16 store, ldc=512 (G build)
// MODE 2: out epilogue (+bias, f32, ldc=512; B offset per batch; masked rows -> bias)
template <int MODE>
__global__ __launch_bounds__(512, 4) void gemm256(const u16* __restrict__ A,
                                                  const u16* __restrict__ Bm,
                                                  u16* __restrict__ outb,
                                                  float* __restrict__ outf,
                                                  const float* __restrict__ bias,
                                                  const int* __restrict__ lengths) {
  __shared__ u16 lA[8192];   // 128x64
  __shared__ u16 lB[16384];  // 256x64

  const int t = threadIdx.x;
  const int w = t >> 6, lane = t & 63, lm = lane & 15, lg = lane >> 4;
  const int wr = w >> 2, wc = w & 3;  // 2 (M) x 4 (N)
  const int row0 = blockIdx.x * 128, col0 = blockIdx.y * 256;

  int L = 0;
  if constexpr (MODE != 1) {
    L = lengths[row0 >> 12];
    if ((row0 & 4095) >= L) {
      if constexpr (MODE == 2) {
        for (int i = t; i < 8192; i += 512) {  // 128 rows x 64 f32x4
          int r = i >> 6, c = (i & 63) * 4;
          *(f32x4*)(outf + (size_t)(row0 + r) * 512 + col0 + c) =
              *(const f32x4*)(bias + col0 + c);
        }
      }
      return;
    }
  }

  const u16* Abase = A + (size_t)row0 * 512;
  const u16* Bbase = Bm + (size_t)col0 * 512;
  if constexpr (MODE == 2) Bbase += (size_t)(row0 >> 12) * 262144;

  // staging geometry (16B granules, XOR-swizzled source, linear LDS dest)
  size_t aoff[2], boff[4];
#pragma unroll
  for (int i = 0; i < 2; ++i) {
    int c = i * 512 + t, r = c >> 3, s = (c & 7) ^ (r & 7);
    aoff[i] = (size_t)r * 512 + s * 8;
  }
#pragma unroll
  for (int i = 0; i < 4; ++i) {
    int c = i * 512 + t, r = c >> 3, s = (c & 7) ^ (r & 7);
    boff[i] = (size_t)r * 512 + s * 8;
  }

  const int swz0 = (lg ^ (lm & 7)) * 8;
  const int swz1 = ((4 + lg) ^ (lm & 7)) * 8;

  f32x4 acc[4][4] = {};

  for (int kt = 0; kt < 8; ++kt) {
    const u16* sa = Abase + kt * 64;
#pragma unroll
    for (int i = 0; i < 2; ++i)
      __builtin_amdgcn_global_load_lds(
          (const __attribute__((address_space(1))) void*)(sa + aoff[i]),
          (__attribute__((address_space(3))) void*)(&lA[(i * 512 + w * 64) * 8]),
          16, 0, 0);
    const u16* sb = Bbase + kt * 64;
#pragma unroll
    for (int i = 0; i < 4; ++i)
      __builtin_amdgcn_global_load_lds(
          (const __attribute__((address_space(1))) void*)(sb + boff[i]),
          (__attribute__((address_space(3))) void*)(&lB[(i * 512 + w * 64) * 8]),
          16, 0, 0);
    __syncthreads();  // drains vmcnt(0): tile resident

    const u16* la = &lA[(wr * 64 + lm) * 64];
    const u16* lb = &lB[(wc * 64 + lm) * 64];
    bf16x8 bfr[2][4];
#pragma unroll
    for (int nf = 0; nf < 4; ++nf) {
      bfr[0][nf] = *(const bf16x8*)(lb + nf * 1024 + swz0);
      bfr[1][nf] = *(const bf16x8*)(lb + nf * 1024 + swz1);
    }
#pragma unroll
    for (int mf = 0; mf < 4; ++mf) {
      bf16x8 af0 = *(const bf16x8*)(la + mf * 1024 + swz0);
      bf16x8 af1 = *(const bf16x8*)(la + mf * 1024 + swz1);
      __builtin_amdgcn_s_setprio(1);
#pragma unroll
      for (int nf = 0; nf < 4; ++nf) {
        acc[mf][nf] = __builtin_amdgcn_mfma_f32_16x16x32_bf16(
            bfr[0][nf], af0, acc[mf][nf], 0, 0, 0);
        acc[mf][nf] = __builtin_amdgcn_mfma_f32_16x16x32_bf16(
            bfr[1][nf], af1, acc[mf][nf], 0, 0, 0);
      }
      __builtin_amdgcn_s_setprio(0);
    }
    __syncthreads();  // all ds_reads done before next-tile overwrite
  }

  // lane holds C[row0 + wr*64 + mf*16 + lm][col0 + wc*64 + nf*16 + lg*4 + r]
  if constexpr (MODE == 0) {
    const int cls = col0 >> 9;  // 0=k, 1=v
#pragma unroll
    for (int mf = 0; mf < 4; ++mf) {
      int grow = row0 + wr * 64 + mf * 16 + lm;
      bool msk = ((grow & 4095) >= L);
      u16* rp = outb + (size_t)grow * 1024 + col0 + wc * 64 + lg * 4;
#pragma unroll
      for (int nf = 0; nf < 4; ++nf) {
        f32x4 v = acc[mf][nf];
        if (msk) {
          float mv = (cls == 0) ? -1e15f : 0.f;
          v[0] = mv; v[1] = mv; v[2] = mv; v[3] = mv;
        }
        union { u16 h[4]; uint2 u; } pk;
        pk.h[0] = f2bf(v[0]); pk.h[1] = f2bf(v[1]);
        pk.h[2] = f2bf(v[2]); pk.h[3] = f2bf(v[3]);
        *(uint2*)(rp + nf * 16) = pk.u;
      }
    }
  } else if constexpr (MODE == 1) {
#pragma unroll
    for (int mf = 0; mf < 4; ++mf) {
      int grow = row0 + wr * 64 + mf * 16 + lm;
      u16* rp = outb + (size_t)grow * 512 + col0 + wc * 64 + lg * 4;
#pragma unroll
      for (int nf = 0; nf < 4; ++nf) {
        f32x4 v = acc[mf][nf];
        union { u16 h[4]; uint2 u; } pk;
        pk.h[0] = f2bf(v[0]); pk.h[1] = f2bf(v[1]);
        pk.h[2] = f2bf(v[2]); pk.h[3] = f2bf(v[3]);
        *(uint2*)(rp + nf * 16) = pk.u;
      }
    }
  } else {
    f32x4 b4[4];
#pragma unroll
    for (int nf = 0; nf < 4; ++nf)
      b4[nf] = *(const f32x4*)(bias + col0 + wc * 64 + nf * 16 + lg * 4);
#pragma unroll
    for (int mf = 0; mf < 4; ++mf) {
      int grow = row0 + wr * 64 + mf * 16 + lm;
      bool msk = ((grow & 4095) >= L);
      float* rp = outf + (size_t)grow * 512 + col0 + wc * 64 + lg * 4;
#pragma unroll
      for (int nf = 0; nf < 4; ++nf) {
        f32x4 v = msk ? b4[nf] : (acc[mf][nf] + b4[nf]);
        *(f32x4*)(rp + nf * 16) = v;
      }
    }
  }
}

// ---------------- ctx partials + denominator partials (length-aware) ----------------
__global__ __launch_bounds__(256) void ctx_gemm(const u16* __restrict__ kv,
                                                float* __restrict__ ctxp,
                                                float* __restrict__ csum,
                                                const int* __restrict__ lengths) {
  int chunk = blockIdx.x;  // 0..7 (512 rows)
  int bh = blockIdx.y;     // 0..63
  int b = bh >> 3, h = bh & 7;
  int L = lengths[b];
  int rows = L - chunk * 512;
  if (rows <= 0) return;
  int ng = rows >= 512 ? 16 : ((rows + 31) >> 5);
  int t = threadIdx.x;
  __shared__ float kx[32][64];
  __shared__ float vx[32][64];
  float acc[4][4] = {};
  float sacc[4] = {};
  int d0 = (t & 15) * 4;
  int e0 = (t >> 4) * 4;
  bool do_sum = ((t >> 4) == 0);
  int srow = t >> 3, scol = (t & 7) * 8;
  const u16* base = kv + (size_t)(b * 4096 + chunk * 512) * 1024 + h * 64;
  for (int g = 0; g < ng; ++g) {
    __syncthreads();
    const u16* kp = base + (size_t)(g * 32 + srow) * 1024 + scol;
    uint4 kvr = *(const uint4*)kp;
    uint4 vvr = *(const uint4*)(kp + 512);
    u32 kw[4] = {kvr.x, kvr.y, kvr.z, kvr.w};
    u32 vw[4] = {vvr.x, vvr.y, vvr.z, vvr.w};
#pragma unroll
    for (int i = 0; i < 4; ++i) {
      float k0 = bf2f(kw[i] & 0xffffu), k1 = bf2f(kw[i] >> 16);
      kx[srow][scol + 2 * i] = exp2f(k0 * L2E);
      kx[srow][scol + 2 * i + 1] = exp2f(k1 * L2E);
      vx[srow][scol + 2 * i] = bf2f(vw[i] & 0xffffu);
      vx[srow][scol + 2 * i + 1] = bf2f(vw[i] >> 16);
    }
    __syncthreads();
#pragma unroll 4
    for (int nn = 0; nn < 32; ++nn) {
      f32x4 p = *(const f32x4*)&kx[nn][d0];
      f32x4 vv = *(const f32x4*)&vx[nn][e0];
      if (do_sum) {
#pragma unroll
        for (int i = 0; i < 4; ++i) sacc[i] += p[i];
      }
#pragma unroll
      for (int i = 0; i < 4; ++i)
#pragma unroll
        for (int j = 0; j < 4; ++j)
          acc[i][j] = __fmaf_rn(p[i], vv[j], acc[i][j]);
    }
  }
  float* outp = ctxp + ((size_t)bh * 8 + chunk) * 4096;
#pragma unroll
  for (int i = 0; i < 4; ++i)
#pragma unroll
    for (int j = 0; j < 4; ++j)
      outp[(d0 + i) * 64 + (e0 + j)] = acc[i][j];
  if (t < 16) {
#pragma unroll
    for (int i = 0; i < 4; ++i)
      csum[((size_t)bh * 8 + chunk) * 64 + d0 + i] = sacc[i];
  }
}

// ---------------- MT[b][dd][64h+d] = SCALE * sum_e (ctx[d,e]/den[d]) * w_out[dd][64h+e] ----------------
__global__ __launch_bounds__(256) void m_gemm(const float* __restrict__ ctxp,
                                              const float* __restrict__ csum,
                                              const float* __restrict__ w_out,
                                              u16* __restrict__ MT,
                                              const int* __restrict__ lengths) {
  int bh = blockIdx.x;
  int grp = blockIdx.y;
  int b = bh >> 3, h = bh & 7;
  int nch = (lengths[b] + 511) >> 9;
  int dd0 = grp * 128;
  int t = threadIdx.x;
  __shared__ short sctx[64 * 64];
  __shared__ short sw[128 * 64];
  {
    const float* cp = ctxp + (size_t)bh * 8 * 4096;
    int i0 = t * 16;
    float vals[16] = {};
    for (int ch = 0; ch < nch; ++ch) {
      const float* p = cp + ch * 4096 + i0;
#pragma unroll
      for (int j = 0; j < 16; j += 4) {
        float4 v = *(const float4*)(p + j);
        vals[j] += v.x; vals[j + 1] += v.y; vals[j + 2] += v.z; vals[j + 3] += v.w;
      }
    }
    int d = t >> 2;
    float den = 0.f;
    for (int ch = 0; ch < nch; ++ch) den += csum[((size_t)bh * 8 + ch) * 64 + d];
    float rin = 1.0f / den;
#pragma unroll
    for (int j = 0; j < 16; ++j) sctx[i0 + j] = (short)f2bf(vals[j] * rin);
  }
  {
#pragma unroll
    for (int j = 0; j < 32; j += 4) {
      int idx = t * 32 + j;
      int row = idx >> 6, col = idx & 63;
      float4 v = *(const float4*)(w_out + (size_t)(dd0 + row) * 512 + h * 64 + col);
      sw[idx] = (short)f2bf(v.x); sw[idx + 1] = (short)f2bf(v.y);
      sw[idx + 2] = (short)f2bf(v.z); sw[idx + 3] = (short)f2bf(v.w);
    }
  }
  __syncthreads();
  int lane = t & 63, w = t >> 6;
  int lm = lane & 15, lk = (lane >> 4) * 8;
  f32x4 acc[2][4] = {};
#pragma unroll
  for (int kk = 0; kk < 2; ++kk) {
    bf16x8 af[2], bfr[4];
#pragma unroll
    for (int mb = 0; mb < 2; ++mb)
      af[mb] = *(const bf16x8*)(sw + (w * 32 + mb * 16 + lm) * 64 + kk * 32 + lk);
#pragma unroll
    for (int nb = 0; nb < 4; ++nb)
      bfr[nb] = *(const bf16x8*)(sctx + (nb * 16 + lm) * 64 + kk * 32 + lk);
#pragma unroll
    for (int mb = 0; mb < 2; ++mb)
#pragma unroll
      for (int nb = 0; nb < 4; ++nb)
        acc[mb][nb] = __builtin_amdgcn_mfma_f32_16x16x32_bf16(af[mb], bfr[nb], acc[mb][nb], 0, 0, 0);
  }
  u16* outp = MT + (size_t)b * 512 * 512;
#pragma unroll
  for (int mb = 0; mb < 2; ++mb)
#pragma unroll
    for (int r = 0; r < 4; ++r) {
      int dd = dd0 + w * 32 + mb * 16 + (lane >> 4) * 4 + r;
#pragma unroll
      for (int nb = 0; nb < 4; ++nb) {
        int c = h * 64 + nb * 16 + lm;
        outp[dd * 512 + c] = f2bf(acc[mb][nb][r] * 0.125f);  // SCALE folded here
      }
    }
}

extern "C" void kernel_launch(void* const* d_in, const int* in_sizes, int n_in,
                              void* d_out, int out_size, void* d_ws, size_t ws_size,
                              hipStream_t stream) {
  const float* x = (const float*)d_in[0];
  const float* w_qkv = (const float*)d_in[1];
  const float* w_out = (const float*)d_in[2];
  const float* b_out = (const float*)d_in[3];
  const int* lengths = (const int*)d_in[4];
  float* out = (float*)d_out;
  char* ws = (char*)d_ws;

  u16* kv     = (u16*)(ws);                     // 32768*1024 bf16 = 67,108,864 B
  u16* xb     = (u16*)(ws + 67108864);          // 33,554,432 B
  u16* wkvb   = (u16*)(ws + 100663296);         // 1024*512 bf16 = 1,048,576 B
  u16* wqT    = (u16*)(ws + 101711872);         // 512*512 bf16 = 524,288 B
  float* ctxp = (float*)(ws + 102236160);       // 8,388,608 B
  float* csum = (float*)(ws + 110624768);       // 131,072 B
  u16* MT     = (u16*)(ws + 110755840);         // 4,194,304 B
  u16* G      = (u16*)(ws + 114950144);         // 4,194,304 B

  cvt_x<<<8192, 256, 0, stream>>>(x, xb, lengths);
  cvt_f32_bf16<<<256, 256, 0, stream>>>(w_qkv + 262144, wkvb, 524288);
  transpose_wq<<<dim3(8, 8), 256, 0, stream>>>(w_qkv, wqT);
  gemm256<0><<<dim3(256, 4), 512, 0, stream>>>(xb, wkvb, kv, nullptr, nullptr, lengths);
  ctx_gemm<<<dim3(8, 64), 256, 0, stream>>>(kv, ctxp, csum, lengths);
  m_gemm<<<dim3(64, 4), 256, 0, stream>>>(ctxp, csum, w_out, MT, lengths);
  gemm256<1><<<dim3(32, 2), 512, 0, stream>>>(MT, wqT, G, nullptr, nullptr, nullptr);
  gemm256<2><<<dim3(256, 2), 512, 0, stream>>>(xb, G, nullptr, out, b_out, lengths);
}

// Round 5
// 162.127 us; speedup vs baseline: 1.4728x; 1.0098x over previous
//
#include <hip/hip_runtime.h>

typedef unsigned short u16;
typedef unsigned int u32;
typedef __bf16 bf16x8 __attribute__((ext_vector_type(8)));
typedef float f32x4 __attribute__((ext_vector_type(4)));

#define L2E 1.44269504088896340736f

static __device__ __forceinline__ u16 f2bf(float f) {
  u32 u = __float_as_uint(f);
  u32 r = (u + 0x7fffu + ((u >> 16) & 1u)) >> 16;
  return (u16)r;
}
static __device__ __forceinline__ float bf2f(u32 bits) {
  return __uint_as_float(bits << 16);
}
static __device__ __forceinline__ u32 trunc_bf(float f) {
  return __float_as_uint(f) >> 16;  // exact when f is a widened bf16 value
}

// ---------------- f32 -> bf16 (for w_qkv k,v rows) ----------------
__global__ __launch_bounds__(256) void cvt_f32_bf16(const float* __restrict__ src,
                                                    u16* __restrict__ dst, int n) {
  int i = (blockIdx.x * 256 + threadIdx.x) * 8;
  if (i + 8 > n) return;
  float4 a = *(const float4*)(src + i);
  float4 b = *(const float4*)(src + i + 4);
  union { u16 h[8]; uint4 v; } o;
  o.h[0] = f2bf(a.x); o.h[1] = f2bf(a.y); o.h[2] = f2bf(a.z); o.h[3] = f2bf(a.w);
  o.h[4] = f2bf(b.x); o.h[5] = f2bf(b.y); o.h[6] = f2bf(b.z); o.h[7] = f2bf(b.w);
  *(uint4*)(dst + i) = o.v;
}

// ---------------- x -> bf16 with row skip ----------------
__global__ __launch_bounds__(256) void cvt_x(const float* __restrict__ src,
                                             u16* __restrict__ dst,
                                             const int* __restrict__ lengths) {
  int i = (blockIdx.x * 256 + threadIdx.x) * 8;  // n = 16777216
  int row = i >> 9;
  if ((row & 4095) >= lengths[row >> 12]) return;
  float4 a = *(const float4*)(src + i);
  float4 b = *(const float4*)(src + i + 4);
  union { u16 h[8]; uint4 v; } o;
  o.h[0] = f2bf(a.x); o.h[1] = f2bf(a.y); o.h[2] = f2bf(a.z); o.h[3] = f2bf(a.w);
  o.h[4] = f2bf(b.x); o.h[5] = f2bf(b.y); o.h[6] = f2bf(b.z); o.h[7] = f2bf(b.w);
  *(uint4*)(dst + i) = o.v;
}

// ---------------- wqT[s][c] = bf16(w_qkv[c][s]), 512x512 ----------------
__global__ __launch_bounds__(256) void transpose_wq(const float* __restrict__ wq,
                                                    u16* __restrict__ wqT) {
  __shared__ u16 tile[64][65];
  int c0 = blockIdx.x * 64, s0 = blockIdx.y * 64;
  int t = threadIdx.x;
  int r = t >> 4, cc = (t & 15) * 4;
#pragma unroll
  for (int i = 0; i < 4; ++i) {
    int row = r + i * 16;
    float4 v = *(const float4*)(wq + (size_t)(c0 + row) * 512 + s0 + cc);
    tile[row][cc] = f2bf(v.x); tile[row][cc + 1] = f2bf(v.y);
    tile[row][cc + 2] = f2bf(v.z); tile[row][cc + 3] = f2bf(v.w);
  }
  __syncthreads();
#pragma unroll
  for (int i = 0; i < 4; ++i) {
    int srow = r + i * 16;
    union { u16 h[4]; uint2 u; } pk;
#pragma unroll
    for (int j = 0; j < 4; ++j) pk.h[j] = tile[cc + j][srow];
    *(uint2*)(wqT + (size_t)(s0 + srow) * 512 + c0 + cc) = pk.u;
  }
}

// ---------------- GEMM: BM=128, BN=256, BK=64, single-buf 48KiB, 2 blocks/CU ----------------
// C[r,c] = sum_k A[r,k]*B[c,k], lda=ldb=512, K=512.
// MODE 0: kv epilogue (k->-1e15 / v->0 for masked rows, bf16, ldc=1024)
// MODE 1: plain bf16 store, ldc=512 (G build)
// MODE 2: out epilogue (+bias, f32, ldc=512; B offset per batch; masked rows -> bias)
template <int MODE>
__global__ __launch_bounds__(512, 4) void gemm256(const u16* __restrict__ A,
                                                  const u16* __restrict__ Bm,
                                                  u16* __restrict__ outb,
                                                  float* __restrict__ outf,
                                                  const float* __restrict__ bias,
                                                  const int* __restrict__ lengths) {
  __shared__ u16 lA[8192];   // 128x64
  __shared__ u16 lB[16384];  // 256x64

  const int t = threadIdx.x;
  const int w = t >> 6, lane = t & 63, lm = lane & 15, lg = lane >> 4;
  const int wr = w >> 2, wc = w & 3;  // 2 (M) x 4 (N)
  const int row0 = blockIdx.x * 128, col0 = blockIdx.y * 256;

  int L = 0;
  if constexpr (MODE != 1) {
    L = lengths[row0 >> 12];
    if ((row0 & 4095) >= L) {
      if constexpr (MODE == 2) {
        for (int i = t; i < 8192; i += 512) {  // 128 rows x 64 f32x4
          int r = i >> 6, c = (i & 63) * 4;
          *(f32x4*)(outf + (size_t)(row0 + r) * 512 + col0 + c) =
              *(const f32x4*)(bias + col0 + c);
        }
      }
      return;
    }
  }

  const u16* Abase = A + (size_t)row0 * 512;
  const u16* Bbase = Bm + (size_t)col0 * 512;
  if constexpr (MODE == 2) Bbase += (size_t)(row0 >> 12) * 262144;

  // staging geometry (16B granules, XOR-swizzled source, linear LDS dest)
  size_t aoff[2], boff[4];
#pragma unroll
  for (int i = 0; i < 2; ++i) {
    int c = i * 512 + t, r = c >> 3, s = (c & 7) ^ (r & 7);
    aoff[i] = (size_t)r * 512 + s * 8;
  }
#pragma unroll
  for (int i = 0; i < 4; ++i) {
    int c = i * 512 + t, r = c >> 3, s = (c & 7) ^ (r & 7);
    boff[i] = (size_t)r * 512 + s * 8;
  }

  const int swz0 = (lg ^ (lm & 7)) * 8;
  const int swz1 = ((4 + lg) ^ (lm & 7)) * 8;

  f32x4 acc[4][4] = {};

  for (int kt = 0; kt < 8; ++kt) {
    const u16* sa = Abase + kt * 64;
#pragma unroll
    for (int i = 0; i < 2; ++i)
      __builtin_amdgcn_global_load_lds(
          (const __attribute__((address_space(1))) void*)(sa + aoff[i]),
          (__attribute__((address_space(3))) void*)(&lA[(i * 512 + w * 64) * 8]),
          16, 0, 0);
    const u16* sb = Bbase + kt * 64;
#pragma unroll
    for (int i = 0; i < 4; ++i)
      __builtin_amdgcn_global_load_lds(
          (const __attribute__((address_space(1))) void*)(sb + boff[i]),
          (__attribute__((address_space(3))) void*)(&lB[(i * 512 + w * 64) * 8]),
          16, 0, 0);
    __syncthreads();  // drains vmcnt(0): tile resident

    const u16* la = &lA[(wr * 64 + lm) * 64];
    const u16* lb = &lB[(wc * 64 + lm) * 64];
    bf16x8 bfr[2][4];
#pragma unroll
    for (int nf = 0; nf < 4; ++nf) {
      bfr[0][nf] = *(const bf16x8*)(lb + nf * 1024 + swz0);
      bfr[1][nf] = *(const bf16x8*)(lb + nf * 1024 + swz1);
    }
#pragma unroll
    for (int mf = 0; mf < 4; ++mf) {
      bf16x8 af0 = *(const bf16x8*)(la + mf * 1024 + swz0);
      bf16x8 af1 = *(const bf16x8*)(la + mf * 1024 + swz1);
      __builtin_amdgcn_s_setprio(1);
#pragma unroll
      for (int nf = 0; nf < 4; ++nf) {
        acc[mf][nf] = __builtin_amdgcn_mfma_f32_16x16x32_bf16(
            bfr[0][nf], af0, acc[mf][nf], 0, 0, 0);
        acc[mf][nf] = __builtin_amdgcn_mfma_f32_16x16x32_bf16(
            bfr[1][nf], af1, acc[mf][nf], 0, 0, 0);
      }
      __builtin_amdgcn_s_setprio(0);
    }
    __syncthreads();  // all ds_reads done before next-tile overwrite
  }

  // lane holds C[row0 + wr*64 + mf*16 + lm][col0 + wc*64 + nf*16 + lg*4 + r]
  if constexpr (MODE == 0) {
    const int cls = col0 >> 9;  // 0=k, 1=v
#pragma unroll
    for (int mf = 0; mf < 4; ++mf) {
      int grow = row0 + wr * 64 + mf * 16 + lm;
      bool msk = ((grow & 4095) >= L);
      u16* rp = outb + (size_t)grow * 1024 + col0 + wc * 64 + lg * 4;
#pragma unroll
      for (int nf = 0; nf < 4; ++nf) {
        f32x4 v = acc[mf][nf];
        if (msk) {
          float mv = (cls == 0) ? -1e15f : 0.f;
          v[0] = mv; v[1] = mv; v[2] = mv; v[3] = mv;
        }
        union { u16 h[4]; uint2 u; } pk;
        pk.h[0] = f2bf(v[0]); pk.h[1] = f2bf(v[1]);
        pk.h[2] = f2bf(v[2]); pk.h[3] = f2bf(v[3]);
        *(uint2*)(rp + nf * 16) = pk.u;
      }
    }
  } else if constexpr (MODE == 1) {
#pragma unroll
    for (int mf = 0; mf < 4; ++mf) {
      int grow = row0 + wr * 64 + mf * 16 + lm;
      u16* rp = outb + (size_t)grow * 512 + col0 + wc * 64 + lg * 4;
#pragma unroll
      for (int nf = 0; nf < 4; ++nf) {
        f32x4 v = acc[mf][nf];
        union { u16 h[4]; uint2 u; } pk;
        pk.h[0] = f2bf(v[0]); pk.h[1] = f2bf(v[1]);
        pk.h[2] = f2bf(v[2]); pk.h[3] = f2bf(v[3]);
        *(uint2*)(rp + nf * 16) = pk.u;
      }
    }
  } else {
    f32x4 b4[4];
#pragma unroll
    for (int nf = 0; nf < 4; ++nf)
      b4[nf] = *(const f32x4*)(bias + col0 + wc * 64 + nf * 16 + lg * 4);
#pragma unroll
    for (int mf = 0; mf < 4; ++mf) {
      int grow = row0 + wr * 64 + mf * 16 + lm;
      bool msk = ((grow & 4095) >= L);
      float* rp = outf + (size_t)grow * 512 + col0 + wc * 64 + lg * 4;
#pragma unroll
      for (int nf = 0; nf < 4; ++nf) {
        f32x4 v = msk ? b4[nf] : (acc[mf][nf] + b4[nf]);
        *(f32x4*)(rp + nf * 16) = v;
      }
    }
  }
}

// ---------------- ctx: MFMA with identity-transpose trick (no LDS staging) ----------------
// ctx[d,e] = sum_n P[n,d]*V[n,e],  P = exp(k);  csum[d] = sum_n P[n,d]
// Per wave, per 32-n group: load P/V rows as row-major A-frags (coalesced),
// transpose in-register via mfma(frag, I) (exact), feed main 16x16x32 MFMAs.
__global__ __launch_bounds__(256, 2) void ctx_gemm(const u16* __restrict__ kv,
                                                   float* __restrict__ ctxp,
                                                   float* __restrict__ csum,
                                                   const int* __restrict__ lengths) {
  int chunk = blockIdx.x;  // 0..7 (512 rows)
  int bh = blockIdx.y;     // 0..63
  int b = bh >> 3, h = bh & 7;
  int L = lengths[b];
  int rows = L - chunk * 512;
  if (rows <= 0) return;
  int ng = rows >= 512 ? 16 : ((rows + 31) >> 5);

  int t = threadIdx.x;
  int w = t >> 6, lane = t & 63, lm = lane & 15, lg = lane >> 4;

  __shared__ float ctx_l[4096];
  __shared__ float den_l[64];
  for (int i = t; i < 4096; i += 256) ctx_l[i] = 0.f;
  if (t < 64) den_l[t] = 0.f;
  __syncthreads();

  // identity B-frags: I1[nn][k] = (k==nn), I2[nn][k] = (k-16==nn); nn=lm, k=lg*8+j
  bf16x8 I1, I2;
  {
    union { u16 h[8]; bf16x8 v; } u1, u2;
#pragma unroll
    for (int j = 0; j < 8; ++j) {
      u1.h[j] = (lg * 8 + j == lm) ? 0x3F80 : 0;
      u2.h[j] = (lg * 8 + j == lm + 16) ? 0x3F80 : 0;
    }
    I1 = u1.v; I2 = u2.v;
  }
  const f32x4 zero = {0.f, 0.f, 0.f, 0.f};

  f32x4 acc[4][4] = {};   // [dt][et]: lane holds ctx[dt*16+lg*4+r][et*16+lm]
  float sacc[4] = {};     // denom partial for d = dt*16+lm (this lane's n subset)

  const u16* kbase = kv + (size_t)(b * 4096 + chunk * 512) * 1024 + h * 64;

  for (int g = w; g < ng; g += 4) {
    // row-major fragment loads: frag[mt][dh] covers rows n0+mt*16+(0..15), d = dh*32+(0..31)
    const u16* rp = kbase + (size_t)(g * 32 + lm) * 1024 + lg * 8;
    bf16x8 praw[2][2], vraw[2][2];
#pragma unroll
    for (int mt = 0; mt < 2; ++mt)
#pragma unroll
      for (int dh = 0; dh < 2; ++dh) {
        const u16* p = rp + (size_t)mt * 16384 + dh * 32;
        praw[mt][dh] = *(const bf16x8*)(p);
        vraw[mt][dh] = *(const bf16x8*)(p + 512);
      }

    // P = exp(k), rounded once to bf16 (the only new rounding point)
    bf16x8 pf[2][2];
#pragma unroll
    for (int mt = 0; mt < 2; ++mt)
#pragma unroll
      for (int dh = 0; dh < 2; ++dh) {
        union { bf16x8 v; u32 w4[4]; } in;
        in.v = praw[mt][dh];
        union { u16 h[8]; bf16x8 v; } o;
#pragma unroll
        for (int i = 0; i < 4; ++i) {
          float a = bf2f(in.w4[i] & 0xffffu) * L2E;
          float bq = bf2f(in.w4[i] >> 16) * L2E;
          o.h[2 * i] = f2bf(exp2f(a));
          o.h[2 * i + 1] = f2bf(exp2f(bq));
        }
        pf[mt][dh] = o.v;
      }

    // in-register transpose: tX[mt][dt], lane holds X[n0+mt*16+lg*4+r][dt*16+lm]
    f32x4 tP[2][4], tV[2][4];
#pragma unroll
    for (int mt = 0; mt < 2; ++mt)
#pragma unroll
      for (int dh = 0; dh < 2; ++dh) {
        tP[mt][dh * 2] = __builtin_amdgcn_mfma_f32_16x16x32_bf16(pf[mt][dh], I1, zero, 0, 0, 0);
        tP[mt][dh * 2 + 1] = __builtin_amdgcn_mfma_f32_16x16x32_bf16(pf[mt][dh], I2, zero, 0, 0, 0);
        tV[mt][dh * 2] = __builtin_amdgcn_mfma_f32_16x16x32_bf16(vraw[mt][dh], I1, zero, 0, 0, 0);
        tV[mt][dh * 2 + 1] = __builtin_amdgcn_mfma_f32_16x16x32_bf16(vraw[mt][dh], I2, zero, 0, 0, 0);
      }

    // denominator partials
#pragma unroll
    for (int dt = 0; dt < 4; ++dt)
#pragma unroll
      for (int mt = 0; mt < 2; ++mt)
        sacc[dt] += tP[mt][dt][0] + tP[mt][dt][1] + tP[mt][dt][2] + tP[mt][dt][3];

    // pack to k-major bf16 frags (lossless truncation: values are exact bf16)
    bf16x8 A2[4], B2[4];
#pragma unroll
    for (int dt = 0; dt < 4; ++dt) {
      union { u32 w4[4]; bf16x8 v; } a, bb;
#pragma unroll
      for (int mt = 0; mt < 2; ++mt) {
        a.w4[mt * 2] = trunc_bf(tP[mt][dt][0]) | (trunc_bf(tP[mt][dt][1]) << 16);
        a.w4[mt * 2 + 1] = trunc_bf(tP[mt][dt][2]) | (trunc_bf(tP[mt][dt][3]) << 16);
        bb.w4[mt * 2] = trunc_bf(tV[mt][dt][0]) | (trunc_bf(tV[mt][dt][1]) << 16);
        bb.w4[mt * 2 + 1] = trunc_bf(tV[mt][dt][2]) | (trunc_bf(tV[mt][dt][3]) << 16);
      }
      A2[dt] = a.v; B2[dt] = bb.v;
    }

    // main contraction over the 32 n (consistent k-slot permutation on both sides)
#pragma unroll
    for (int dt = 0; dt < 4; ++dt)
#pragma unroll
      for (int et = 0; et < 4; ++et)
        acc[dt][et] = __builtin_amdgcn_mfma_f32_16x16x32_bf16(A2[dt], B2[et], acc[dt][et], 0, 0, 0);
  }

  // reduce denominator across lane groups (lanes lm,+16,+32,+48 share d)
#pragma unroll
  for (int dt = 0; dt < 4; ++dt) {
    float s = sacc[dt];
    s += __shfl_xor(s, 16);
    s += __shfl_xor(s, 32);
    if (lg == 0) atomicAdd(&den_l[dt * 16 + lm], s);
  }

  // accumulate ctx partials across the 4 waves
#pragma unroll
  for (int dt = 0; dt < 4; ++dt)
#pragma unroll
    for (int et = 0; et < 4; ++et)
#pragma unroll
      for (int r = 0; r < 4; ++r)
        atomicAdd(&ctx_l[(dt * 16 + lg * 4 + r) * 64 + et * 16 + lm], acc[dt][et][r]);
  __syncthreads();

  float* outp = ctxp + ((size_t)bh * 8 + chunk) * 4096;
#pragma unroll
  for (int i = 0; i < 4; ++i)
    *(f32x4*)(outp + t * 16 + i * 4) = *(const f32x4*)(ctx_l + t * 16 + i * 4);
  if (t < 64) csum[((size_t)bh * 8 + chunk) * 64 + t] = den_l[t];
}

// ---------------- MT[b][dd][64h+d] = SCALE * sum_e (ctx[d,e]/den[d]) * w_out[dd][64h+e] ----------------
__global__ __launch_bounds__(256) void m_gemm(const float* __restrict__ ctxp,
                                              const float* __restrict__ csum,
                                              const float* __restrict__ w_out,
                                              u16* __restrict__ MT,
                                              const int* __restrict__ lengths) {
  int bh = blockIdx.x;
  int grp = blockIdx.y;
  int b = bh >> 3, h = bh & 7;
  int nch = (lengths[b] + 511) >> 9;
  int dd0 = grp * 128;
  int t = threadIdx.x;
  __shared__ short sctx[64 * 64];
  __shared__ short sw[128 * 64];
  {
    const float* cp = ctxp + (size_t)bh * 8 * 4096;
    int i0 = t * 16;
    float vals[16] = {};
    for (int ch = 0; ch < nch; ++ch) {
      const float* p = cp + ch * 4096 + i0;
#pragma unroll
      for (int j = 0; j < 16; j += 4) {
        float4 v = *(const float4*)(p + j);
        vals[j] += v.x; vals[j + 1] += v.y; vals[j + 2] += v.z; vals[j + 3] += v.w;
      }
    }
    int d = t >> 2;
    float den = 0.f;
    for (int ch = 0; ch < nch; ++ch) den += csum[((size_t)bh * 8 + ch) * 64 + d];
    float rin = 1.0f / den;
#pragma unroll
    for (int j = 0; j < 16; ++j) sctx[i0 + j] = (short)f2bf(vals[j] * rin);
  }
  {
#pragma unroll
    for (int j = 0; j < 32; j += 4) {
      int idx = t * 32 + j;
      int row = idx >> 6, col = idx & 63;
      float4 v = *(const float4*)(w_out + (size_t)(dd0 + row) * 512 + h * 64 + col);
      sw[idx] = (short)f2bf(v.x); sw[idx + 1] = (short)f2bf(v.y);
      sw[idx + 2] = (short)f2bf(v.z); sw[idx + 3] = (short)f2bf(v.w);
    }
  }
  __syncthreads();
  int lane = t & 63, w = t >> 6;
  int lm = lane & 15, lk = (lane >> 4) * 8;
  f32x4 acc[2][4] = {};
#pragma unroll
  for (int kk = 0; kk < 2; ++kk) {
    bf16x8 af[2], bfr[4];
#pragma unroll
    for (int mb = 0; mb < 2; ++mb)
      af[mb] = *(const bf16x8*)(sw + (w * 32 + mb * 16 + lm) * 64 + kk * 32 + lk);
#pragma unroll
    for (int nb = 0; nb < 4; ++nb)
      bfr[nb] = *(const bf16x8*)(sctx + (nb * 16 + lm) * 64 + kk * 32 + lk);
#pragma unroll
    for (int mb = 0; mb < 2; ++mb)
#pragma unroll
      for (int nb = 0; nb < 4; ++nb)
        acc[mb][nb] = __builtin_amdgcn_mfma_f32_16x16x32_bf16(af[mb], bfr[nb], acc[mb][nb], 0, 0, 0);
  }
  u16* outp = MT + (size_t)b * 512 * 512;
#pragma unroll
  for (int mb = 0; mb < 2; ++mb)
#pragma unroll
    for (int r = 0; r < 4; ++r) {
      int dd = dd0 + w * 32 + mb * 16 + (lane >> 4) * 4 + r;
#pragma unroll
      for (int nb = 0; nb < 4; ++nb) {
        int c = h * 64 + nb * 16 + lm;
        outp[dd * 512 + c] = f2bf(acc[mb][nb][r] * 0.125f);  // SCALE folded here
      }
    }
}

extern "C" void kernel_launch(void* const* d_in, const int* in_sizes, int n_in,
                              void* d_out, int out_size, void* d_ws, size_t ws_size,
                              hipStream_t stream) {
  const float* x = (const float*)d_in[0];
  const float* w_qkv = (const float*)d_in[1];
  const float* w_out = (const float*)d_in[2];
  const float* b_out = (const float*)d_in[3];
  const int* lengths = (const int*)d_in[4];
  float* out = (float*)d_out;
  char* ws = (char*)d_ws;

  u16* kv     = (u16*)(ws);                     // 32768*1024 bf16 = 67,108,864 B
  u16* xb     = (u16*)(ws + 67108864);          // 33,554,432 B
  u16* wkvb   = (u16*)(ws + 100663296);         // 1,048,576 B
  u16* wqT    = (u16*)(ws + 101711872);         // 524,288 B
  float* ctxp = (float*)(ws + 102236160);       // 8,388,608 B
  float* csum = (float*)(ws + 110624768);       // 131,072 B
  u16* MT     = (u16*)(ws + 110755840);         // 4,194,304 B
  u16* G      = (u16*)(ws + 114950144);         // 4,194,304 B

  cvt_x<<<8192, 256, 0, stream>>>(x, xb, lengths);
  cvt_f32_bf16<<<256, 256, 0, stream>>>(w_qkv + 262144, wkvb, 524288);
  transpose_wq<<<dim3(8, 8), 256, 0, stream>>>(w_qkv, wqT);
  gemm256<0><<<dim3(256, 4), 512, 0, stream>>>(xb, wkvb, kv, nullptr, nullptr, lengths);
  ctx_gemm<<<dim3(8, 64), 256, 0, stream>>>(kv, ctxp, csum, lengths);
  m_gemm<<<dim3(64, 4), 256, 0, stream>>>(ctxp, csum, w_out, MT, lengths);
  gemm256<1><<<dim3(32, 2), 512, 0, stream>>>(MT, wqT, G, nullptr, nullptr, nullptr);
  gemm256<2><<<dim3(256, 2), 512, 0, stream>>>(xb, G, nullptr, out, b_out, lengths);
}